// Round 10
// baseline (355.328 us; speedup 1.0000x reference)
//
#include <hip/hip_runtime.h>

// AdjointODE: h += dt * ( tanh(h@W1+b1) @ W2 + b2 ), 50 Euler steps.
// BATCH=32768, DIM=128, HID=256.
// ROUND 10: FP8 (e4m3) weights AND matmul operands -- LDS reads drop from
// b128 to b64 (round-9 profile: LDS read pipe saturated at ~13.9k cyc/step/CU
// = the wall). mfma_f32_16x16x32_fp8_fp8, same shape/count as bf16 round 9.
// Scaling keeps e4m3 in range: W1 stored *16*TSCALE, W2 stored *16, act
// packed as 16*tanh (in [-16,16]; dt*tanh would be subnormal-dead), state h
// packed raw. mm2 -> separate acc; h += dt*b2 + (dt/256)*acc.
// b1 accumulator-init register-resident (64 VGPR; kills 16 b128/step).
// Layout structure unchanged from r9: fragment-linear LDS (conflict-free
// vectorized staging + immediate-offset b64 reads), positional K-order map
// shared by A storage and B packing, 256x512 (2 waves/SIMD TLP win from r8),
// h fp32-resident. Outer loops unroll-1 (round-3 lesson).
// Spill canary: FETCH ~9.3 MB.

typedef __attribute__((ext_vector_type(4))) float float4v;
typedef __attribute__((ext_vector_type(2))) int int2v;

union F8 { long l; int2v i; };

// LDS map (bytes)
#define W1F_OFF 0        // 64 frags (nt*4+c) x 512 B = 32 KB
#define W2F_OFF 32768    // 64 frags (p*8+tb) x 512 B = 32 KB
#define DT_OFF  65536    // f32[64]
#define LDS_BYTES 65792

#define TSCALE 2.8853900817779268f  // 2/ln2: tanh(x) = 1 - 2/(exp2(x*TSCALE)+1)
#define WSC 16.0f                   // fp8 pre-scale (stay above e4m3 min-normal)

__device__ __forceinline__ int pk4_fp8(float a, float b, float c, float d) {
  int v = __builtin_amdgcn_cvt_pk_fp8_f32(a, b, 0, false);   // bytes 0,1
  v = __builtin_amdgcn_cvt_pk_fp8_f32(c, d, v, true);        // bytes 2,3
  return v;
}

// fp8 frag for one 32-K chunk from two C-layout float4 tiles (even, odd).
// Byte j (j<4): logical K = base + q*4 + j ; (j>=4): base + 16 + q*4 + (j-4).
// Weight staging uses the identical slot->k map => positional dot correct.
__device__ __forceinline__ long packfrag8(float4v e, float4v o) {
  F8 f;
  f.i.x = pk4_fp8(e.x, e.y, e.z, e.w);
  f.i.y = pk4_fp8(o.x, o.y, o.z, o.w);
  return f.l;
}

#define MFMA8(a, b, c) __builtin_amdgcn_mfma_f32_16x16x32_fp8_fp8(a, b, c, 0, 0, 0)

extern "C" __global__ __launch_bounds__(512)
void ode_kernel(const float* __restrict__ inp, const float* __restrict__ ts,
                const float* __restrict__ W1, const float* __restrict__ b1,
                const float* __restrict__ W2, const float* __restrict__ b2,
                float* __restrict__ out) {
  __shared__ __align__(16) char ldsb[LDS_BYTES];
  float* dtf = (float*)(ldsb + DT_OFF);

  const int tid = threadIdx.x;
  const int lane = tid & 63, wave = tid >> 6;
  const int ln = lane & 15;  // batch-row within wave's 16
  const int q = lane >> 4;   // quad
  const int row = blockIdx.x * 128 + wave * 16 + ln;

  // ---- stage W1 frags (fp8, *16*TSCALE): pi = fid*64 + L ----
  #pragma unroll 1
  for (int it = 0; it < 8; it++) {
    const int pi = it * 512 + tid;  // [0, 4096)
    const int fid = pi >> 6, L = pi & 63;
    const int nt = fid >> 2, c = fid & 3;
    const int lf = L & 15, qf = L >> 4;
    const int n = nt * 16 + lf;       // hid (A-frag m-row)
    const int kb = c * 32 + qf * 4;   // logical dim base
    const float sc = WSC * TSCALE;
    float4v e = {W1[(kb + 0) * 256 + n] * sc, W1[(kb + 1) * 256 + n] * sc,
                 W1[(kb + 2) * 256 + n] * sc, W1[(kb + 3) * 256 + n] * sc};
    float4v o = {W1[(kb + 16) * 256 + n] * sc, W1[(kb + 17) * 256 + n] * sc,
                 W1[(kb + 18) * 256 + n] * sc, W1[(kb + 19) * 256 + n] * sc};
    *(long*)(ldsb + W1F_OFF + pi * 8) = packfrag8(e, o);
  }
  // ---- stage W2 frags (fp8, *16): fid = p*8 + tb ----
  #pragma unroll 1
  for (int it = 0; it < 8; it++) {
    const int pi = it * 512 + tid;
    const int fid = pi >> 6, L = pi & 63;
    const int p = fid >> 3, tb = fid & 7;
    const int lf = L & 15, qf = L >> 4;
    const int dd = tb * 16 + lf;      // output-dim (A-frag m-row)
    const int kb = p * 32 + qf * 4;   // logical hid base
    float4v e = {W2[(kb + 0) * 128 + dd] * WSC, W2[(kb + 1) * 128 + dd] * WSC,
                 W2[(kb + 2) * 128 + dd] * WSC, W2[(kb + 3) * 128 + dd] * WSC};
    float4v o = {W2[(kb + 16) * 128 + dd] * WSC, W2[(kb + 17) * 128 + dd] * WSC,
                 W2[(kb + 18) * 128 + dd] * WSC, W2[(kb + 19) * 128 + dd] * WSC};
    *(long*)(ldsb + W2F_OFF + pi * 8) = packfrag8(e, o);
  }
  if (tid < 50) dtf[tid] = ts[tid + 1] - ts[tid];

  // ---- resident biases: b1v = 16*TSCALE*b1 (mm1 C-init), b2v raw ----
  float4v b1v[16], b2v[8];
  #pragma unroll
  for (int nt = 0; nt < 16; nt++) {
    float4v v = *(const float4v*)&b1[nt * 16 + q * 4];
    b1v[nt] = v * (WSC * TSCALE);
  }
  #pragma unroll
  for (int tb = 0; tb < 8; tb++)
    b2v[tb] = *(const float4v*)&b2[tb * 16 + q * 4];

  // ---- load h: 16x16 C-layout. h4[tb][r] = h[row][tb*16 + q*4 + r] ----
  float4v h4[8];
  #pragma unroll
  for (int tb = 0; tb < 8; tb++)
    h4[tb] = *(const float4v*)&inp[row * 128 + tb * 16 + q * 4];

  __syncthreads();  // the only barrier

  const long* w1f = (const long*)(ldsb + W1F_OFF) + lane;
  const long* w2f = (const long*)(ldsb + W2F_OFF) + lane;

  #pragma unroll 1
  for (int s = 0; s < 50; s++) {
    const float dt = dtf[s];
    const float dts = dt * (1.0f / 256.0f);  // undo 16*16 operand scales

    // ---- state -> 4 fp8 B-frags (pure register packing) ----
    long hb[4];
    #pragma unroll
    for (int kc = 0; kc < 4; kc++)
      hb[kc] = packfrag8(h4[2 * kc], h4[2 * kc + 1]);

    float4v acc[8];
    #pragma unroll
    for (int tb = 0; tb < 8; tb++) acc[tb] = (float4v){0.f, 0.f, 0.f, 0.f};

    // ---- 8 hid-pairs (32 hid each): mm1 -> tanh -> mm2 ----
    #pragma unroll 1
    for (int p = 0; p < 8; p++) {
      const int nt0 = 2 * p, nt1 = 2 * p + 1;
      long wA[4], wB[4];
      #pragma unroll
      for (int c = 0; c < 4; c++) {
        wA[c] = w1f[(nt0 * 4 + c) * 64];
        wB[c] = w1f[(nt1 * 4 + c) * 64];
      }
      // g (scaled by 16*TSCALE), init = 16*TSCALE*b1; two independent 4-chains
      float4v g0 = b1v[nt0], g1 = b1v[nt1];
      #pragma unroll
      for (int c = 0; c < 4; c++) {
        g0 = MFMA8(wA[c], hb[c], g0);
        g1 = MFMA8(wB[c], hb[c], g1);
      }

      // W2 frags for this 32-K chunk (issued before tanh)
      long w2r[8];
      #pragma unroll
      for (int tb = 0; tb < 8; tb++)
        w2r[tb] = w2f[(p * 8 + tb) * 64];

      // 16*tanh = 16 - 32*rcp(exp2(g/16) + 1)
      float4v a0, a1;
      #pragma unroll
      for (int r = 0; r < 4; r++) {
        a0[r] = fmaf(__builtin_amdgcn_rcpf(
                    __builtin_amdgcn_exp2f(g0[r] * 0.0625f) + 1.0f), -32.f, 16.f);
        a1[r] = fmaf(__builtin_amdgcn_rcpf(
                    __builtin_amdgcn_exp2f(g1[r] * 0.0625f) + 1.0f), -32.f, 16.f);
      }
      long af = packfrag8(a0, a1);

      // mm2: acc += (16*act)-chunk @ (16*W2)-chunk
      #pragma unroll
      for (int tb = 0; tb < 8; tb++)
        acc[tb] = MFMA8(w2r[tb], af, acc[tb]);
    }

    // ---- h += dt*b2 + (dt/256)*acc ----
    #pragma unroll
    for (int tb = 0; tb < 8; tb++)
      #pragma unroll
      for (int r = 0; r < 4; r++)
        h4[tb][r] = fmaf(dts, acc[tb][r], fmaf(dt, b2v[tb][r], h4[tb][r]));
  }

  // ---- store ----
  #pragma unroll
  for (int tb = 0; tb < 8; tb++)
    *(float4v*)&out[row * 128 + tb * 16 + q * 4] = h4[tb];
}

extern "C" void kernel_launch(void* const* d_in, const int* in_sizes, int n_in,
                              void* d_out, int out_size, void* d_ws, size_t ws_size,
                              hipStream_t stream) {
  const float* inp = (const float*)d_in[0];
  const float* ts  = (const float*)d_in[1];
  const float* W1  = (const float*)d_in[2];
  const float* b1  = (const float*)d_in[3];
  const float* W2  = (const float*)d_in[4];
  const float* b2  = (const float*)d_in[5];
  hipLaunchKernelGGL(ode_kernel, dim3(256), dim3(512), 0, stream,
                     inp, ts, W1, b1, W2, b2, (float*)d_out);
}